// Round 1
// 471.457 us; speedup vs baseline: 1.1418x; 1.1418x over previous
//
#include <hip/hip_runtime.h>

typedef _Float16 h16;
typedef _Float16 half8 __attribute__((ext_vector_type(8)));
typedef float floatx4 __attribute__((ext_vector_type(4)));

#define B_TOT 1024
#define T_STEPS 24
#define F 64          // FILTERS
#define C2 128        // 2*FILTERS
#define FEAT 15
#define L_ENC 168
#define HID 128
#define R 16          // batch rows per block = MFMA M tile
#define BLK 256       // 4 waves
#define FP 72         // padded row stride (h16) for 16-row activation tiles

__device__ __forceinline__ floatx4 mfma16(half8 a, half8 b, floatx4 c) {
  return __builtin_amdgcn_mfma_f32_16x16x32_f16(a, b, c, 0, 0, 0);
}

// Barrier WITHOUT the __syncthreads vmcnt(0) drain: LDS-producer visibility only.
// Global prefetches (W5 frags / enc states / dec_feat) stay in flight across it.
// Single asm blob so the compiler can't separate waitcnt from barrier; "memory"
// clobber pins all LDS stores before it. All call sites are in uniform CF.
#define BAR() asm volatile("s_waitcnt lgkmcnt(0)\n\ts_barrier" ::: "memory")

// tanh via hardware exp2 + rcp (~1 ulp each; error << f16 budget)
__device__ __forceinline__ float tanh_fast(float x) {
  float cx = fminf(fmaxf(x, -15.f), 15.f);
  float e  = __builtin_amdgcn_exp2f(-2.885390081777927f * cx);   // e^{-2x}
  return (1.f - e) * __builtin_amdgcn_rcpf(1.f + e);
}
// tanh(f) * sigmoid(g) with a single rcp
__device__ __forceinline__ float gate_fast(float f, float g) {
  float cf = fminf(fmaxf(f, -15.f), 15.f);
  float cg = fminf(fmaxf(g, -30.f), 30.f);
  float ef = __builtin_amdgcn_exp2f(-2.885390081777927f * cf);   // e^{-2f}
  float eg = __builtin_amdgcn_exp2f(-1.4426950408889634f * cg);  // e^{-g}
  return (1.f - ef) * __builtin_amdgcn_rcpf((1.f + ef) * (1.f + eg));
}

// prep: W5 (384x128 f32, row-major) -> f16 B-frag layout in ws:
// idx = ((ktg*8 + nt)*64 + lane)*8 + j ; value = W5[ktg*32 + (lane>>4)*8 + j][nt*16 + (lane&15)]
__global__ void prep_w5(const float* __restrict__ gW5, h16* __restrict__ wsW5) {
  int t = blockIdx.x * 256 + threadIdx.x;     // 0..6143
  if (t >= 12 * 8 * 64) return;
  int lane = t & 63, nt = (t >> 6) & 7, ktg = t >> 9;
  int n  = nt * 16 + (lane & 15);
  int kb = ktg * 32 + (lane >> 4) * 8;
  half8 v;
  #pragma unroll
  for (int j = 0; j < 8; ++j) v[j] = (h16)gW5[(size_t)(kb + j) * C2 + n];
  *(half8*)&wsW5[(size_t)t * 8] = v;
}

// v7: latency-chain attack.
//  - raw s_barrier (no vmcnt drain) -> global prefetches survive barriers
//  - W1/W2/W3/W4/W5 fragments + all biases hoisted to registers (loop-invariant;
//    1 block/CU -> full 512-VGPR budget via __launch_bounds__(256,1))
//  - x32 residual master -> per-thread registers (fixed (row,col) per lane)
//  - exp2/rcp-based tanh & gate (ocml tanhf/expf was ~80 instrs per gate)
//  - dec_feat load issued at step top, LDS write deferred to B3
__global__ __launch_bounds__(BLK, 1) void decoder_v7(
    const float* __restrict__ dec_feat,   // (B,24,15)
    const float* __restrict__ dec_init,   // (B,1)
    const float* __restrict__ enc,        // (6,B,168,64)
    const float* __restrict__ gW1, const float* __restrict__ gb1,
    const float* __restrict__ gW2, const float* __restrict__ gb2,
    const float* __restrict__ gW3,
    const float* __restrict__ gW4, const float* __restrict__ gb4,
    const h16*  __restrict__ wsW5, const float* __restrict__ gb5,
    const float* __restrict__ gW6, const float* __restrict__ gb6,
    float* __restrict__ out)              // (B,24)
{
  __shared__ alignas(16) h16 ringL[31][R][FP];    // ~70KB: layer i base = 2^i-1 slots
  __shared__ alignas(16) h16 xH[R][FP];
  __shared__ alignas(16) h16 gatedH[R][FP];
  __shared__ alignas(16) h16 skipH[R][FP];
  __shared__ alignas(16) h16 curH[R][40];         // k 0..31 used (16..31 zero), pad to 40
  __shared__ float ypart[4][R];

  const int tid  = threadIdx.x;
  const int w    = tid >> 6;        // wave 0..3
  const int lane = tid & 63;
  const int m16  = lane & 15;
  const int q    = lane >> 4;
  const int q8   = q * 8;
  const int b0   = blockIdx.x * R;
  const int col  = w * 16 + m16;    // 0..63, fixed per thread
  const int mm0  = tid / FEAT;
  const int f0   = tid - mm0 * FEAT;
  const bool featT = (tid < R * FEAT);

  // ---- loop-invariant weights -> registers ----
  // W1 B-frag (nt = w): B[k][n], k = q8+j (k>=16 zero-padded)
  half8 rW1;
  #pragma unroll
  for (int j = 0; j < 8; ++j) {
    int k = q8 + j;
    rW1[j] = (k < 16) ? (h16)gW1[k * F + col] : (h16)0.0f;
  }
  // W2/W3/W4 B-frags for nt = w (h=0) and nt = w+4 (h=1), kt = 0,1
  half8 rW2[2][2], rW3[2][2], rW4[2][2];
  #pragma unroll
  for (int h = 0; h < 2; ++h) {
    int n = (w + 4 * h) * 16 + m16;
    #pragma unroll
    for (int kt = 0; kt < 2; ++kt) {
      half8 v2, v3, v4;
      #pragma unroll
      for (int j = 0; j < 8; ++j) {
        int k = kt * 32 + q8 + j;
        v2[j] = (h16)gW2[k * C2 + n];
        v3[j] = (h16)gW3[k * C2 + n];
        v4[j] = (h16)gW4[k * C2 + n];
      }
      rW2[h][kt] = v2; rW3[h][kt] = v3; rW4[h][kt] = v4;
    }
  }
  // W5 B-frags, all 6 skip-chunks (96 VGPRs)
  half8 w5r[6][4];
  #pragma unroll
  for (int i = 0; i < 6; ++i)
    #pragma unroll
    for (int kt = 0; kt < 2; ++kt)
      #pragma unroll
      for (int nn = 0; nn < 2; ++nn)
        w5r[i][kt * 2 + nn] =
            *(const half8*)&wsW5[(size_t)((((2 * i + kt) * 8) + (w + 4 * nn)) * 64 + lane) * 8];

  // per-thread bias / W6 scalars (col fixed per lane)
  const float rb1  = gb1[col];
  const float rb2f = gb2[col], rb2g = gb2[64 + col];
  const float rb4s = gb4[col], rb4r = gb4[64 + col];
  const float rb5a = gb5[col], rb5b = gb5[64 + col];
  const float rw6a = gW6[col], rw6b = gW6[64 + col];
  const float rb6  = gb6[0];

  { int mm = tid >> 4, kk = 16 + (tid & 15); curH[mm][kk] = (h16)0.0f; }  // zero pad region
  if (featT) curH[mm0][1 + f0] = (h16)dec_feat[(b0 + mm0) * (T_STEPS * FEAT) + f0];
  if (tid < R) curH[tid][0] = (h16)dec_init[b0 + tid];
  __syncthreads();

  const int rbase[6] = {0, 1, 3, 7, 15, 0};   // ring slot base per layer (i<5)

  // stat A-frag loader: ring (LDS) if t>=d else encoder (global fp32 -> f16)
  auto loadStat = [&](half8* dst, int i, int d, int base, int t) {
    if (t >= d) {
      const h16* p = &ringL[base + (t & (d - 1))][m16][0];
      dst[0] = *(const half8*)(p + q8);
      dst[1] = *(const half8*)(p + 32 + q8);
    } else {
      const float* ep = enc + (((size_t)i * B_TOT + b0 + m16) * L_ENC + (L_ENC + t - d)) * F;
      #pragma unroll
      for (int kt = 0; kt < 2; ++kt) {
        float4 e0 = *(const float4*)(ep + kt * 32 + q8);
        float4 e1 = *(const float4*)(ep + kt * 32 + q8 + 4);
        half8 hv;
        hv[0] = (h16)e0.x; hv[1] = (h16)e0.y; hv[2] = (h16)e0.z; hv[3] = (h16)e0.w;
        hv[4] = (h16)e1.x; hv[5] = (h16)e1.y; hv[6] = (h16)e1.z; hv[7] = (h16)e1.w;
        dst[kt] = hv;
      }
    }
  };

  float xr[4];   // fp32 residual-stream master, (row=q*4+j, col) fixed per lane

  for (int t = 0; t < T_STEPS; ++t) {
    // early-issue next step's features; LDS write deferred to B3 (latency hides under 6 layers)
    float nf = 0.f;
    const bool doFeat = featT && (t + 1 < T_STEPS);
    if (doFeat) nf = dec_feat[(b0 + mm0) * (T_STEPS * FEAT) + (t + 1) * FEAT + f0];

    // ---- W1: x = tanh(cur @ W1 + b1) ----
    half8 aCur = *(const half8*)&curH[m16][q8];
    floatx4 accX = {0.f, 0.f, 0.f, 0.f};
    accX = mfma16(aCur, rW1, accX);
    half8 stat[2];
    loadStat(stat, 0, 1, 0, t);               // stat for dilation 0
    #pragma unroll
    for (int j = 0; j < 4; ++j) {
      float v = tanh_fast(accX[j] + rb1);
      xr[j] = v;
      xH[q * 4 + j][col] = (h16)v;
    }
    BAR();                                    // B1: xH ready

    floatx4 hAccA = {0.f, 0.f, 0.f, 0.f};     // W5 acc, nt=w
    floatx4 hAccB = {0.f, 0.f, 0.f, 0.f};     // W5 acc, nt=w+4

    #pragma unroll
    for (int i = 0; i < 6; ++i) {
      const int d = 1 << i;
      half8 xA0 = *(const half8*)&xH[m16][q8];
      half8 xA1 = *(const half8*)&xH[m16][32 + q8];
      half8 stN[2];
      if (i < 5) loadStat(stN, i + 1, d << 1, rbase[i + 1], t);  // prefetch next dilation

      // phase A: dil = stat@W2 + x@W3 (+b2)
      floatx4 aF = {0.f, 0.f, 0.f, 0.f}, aG = {0.f, 0.f, 0.f, 0.f};
      aF = mfma16(stat[0], rW2[0][0], aF);
      aF = mfma16(stat[1], rW2[0][1], aF);
      aF = mfma16(xA0,     rW3[0][0], aF);
      aF = mfma16(xA1,     rW3[0][1], aF);
      aG = mfma16(stat[0], rW2[1][0], aG);
      aG = mfma16(stat[1], rW2[1][1], aG);
      aG = mfma16(xA0,     rW3[1][0], aG);
      aG = mfma16(xA1,     rW3[1][1], aG);
      #pragma unroll
      for (int j = 0; j < 4; ++j)
        gatedH[q * 4 + j][col] = (h16)gate_fast(aF[j] + rb2f, aG[j] + rb2g);
      BAR();                                  // B2a: gatedH ready

      // phase B: o = gated @ W4 + b4 ; skip cols 0..63, residual 64..127
      half8 gA0 = *(const half8*)&gatedH[m16][q8];
      half8 gA1 = *(const half8*)&gatedH[m16][32 + q8];
      floatx4 oS = {0.f, 0.f, 0.f, 0.f}, oR = {0.f, 0.f, 0.f, 0.f};
      oS = mfma16(gA0, rW4[0][0], oS);
      oS = mfma16(gA1, rW4[0][1], oS);
      oR = mfma16(gA0, rW4[1][0], oR);
      oR = mfma16(gA1, rW4[1][1], oR);
      #pragma unroll
      for (int j = 0; j < 4; ++j) {
        int row = q * 4 + j;
        float s = oS[j] + rb4s;
        skipH[row][col] = (h16)fmaxf(s, 0.0f);
        float xn = xr[j] + oR[j] + rb4r;      // fp32 master update
        xr[j] = xn;
        h16 hx = (h16)xn;
        xH[row][col] = hx;
        if (i < 5) ringL[rbase[i] + (t & (d - 1))][row][col] = hx;
      }
      BAR();                                  // B2b: skipH/xH/ring ready

      // W5 skip-chunk i (register B-frags)
      half8 sk0 = *(const half8*)&skipH[m16][q8];
      half8 sk1 = *(const half8*)&skipH[m16][32 + q8];
      hAccA = mfma16(sk0, w5r[i][0], hAccA);
      hAccA = mfma16(sk1, w5r[i][2], hAccA);
      hAccB = mfma16(sk0, w5r[i][1], hAccB);
      hAccB = mfma16(sk1, w5r[i][3], hAccB);

      if (i < 5) { stat[0] = stN[0]; stat[1] = stN[1]; }
    }

    // ---- h = relu(hAcc + b5); y = h @ W6 + b6 ----
    {
      floatx4 vv;
      #pragma unroll
      for (int j = 0; j < 4; ++j) {
        float ha = fmaxf(hAccA[j] + rb5a, 0.0f);
        float hb = fmaxf(hAccB[j] + rb5b, 0.0f);
        vv[j] = ha * rw6a + hb * rw6b;
      }
      #pragma unroll
      for (int off = 1; off < 16; off <<= 1) {
        #pragma unroll
        for (int j = 0; j < 4; ++j) vv[j] += __shfl_xor(vv[j], off, 16);
      }
      if (m16 == 0) {
        #pragma unroll
        for (int j = 0; j < 4; ++j) ypart[w][q * 4 + j] = vv[j];
      }
    }
    if (doFeat) curH[mm0][1 + f0] = (h16)nf;  // deferred feature write
    BAR();                                    // B3: ypart ready
    if (tid < R) {
      float y = ypart[0][tid] + ypart[1][tid] + ypart[2][tid] + ypart[3][tid] + rb6;
      out[(b0 + tid) * T_STEPS + t] = y;
      curH[tid][0] = (h16)y;
    }
    BAR();                                    // B4: curH ready for next step
  }
}

extern "C" void kernel_launch(void* const* d_in, const int* in_sizes, int n_in,
                              void* d_out, int out_size, void* d_ws, size_t ws_size,
                              hipStream_t stream) {
  const float* dec_feat = (const float*)d_in[0];
  const float* dec_init = (const float*)d_in[1];
  const float* enc      = (const float*)d_in[2];
  const float* W1 = (const float*)d_in[3];
  const float* b1 = (const float*)d_in[4];
  const float* W2 = (const float*)d_in[5];
  const float* b2 = (const float*)d_in[6];
  const float* W3 = (const float*)d_in[7];
  const float* W4 = (const float*)d_in[8];
  const float* b4 = (const float*)d_in[9];
  const float* W5 = (const float*)d_in[10];
  const float* b5 = (const float*)d_in[11];
  const float* W6 = (const float*)d_in[12];
  const float* b6 = (const float*)d_in[13];
  float* out = (float*)d_out;
  h16* wsW5 = (h16*)d_ws;

  prep_w5<<<24, 256, 0, stream>>>(W5, wsW5);
  decoder_v7<<<dim3(B_TOT / R), dim3(BLK), 0, stream>>>(
      dec_feat, dec_init, enc, W1, b1, W2, b2, W3, W4, b4, wsW5, b5, W6, b6, out);
}

// Round 3
// 447.230 us; speedup vs baseline: 1.2036x; 1.0542x over previous
//
#include <hip/hip_runtime.h>

typedef _Float16 h16;
typedef _Float16 half4 __attribute__((ext_vector_type(4)));
typedef _Float16 half8 __attribute__((ext_vector_type(8)));
typedef float floatx4 __attribute__((ext_vector_type(4)));

#define B_TOT 1024
#define T_STEPS 24
#define F 64          // FILTERS
#define C2 128        // 2*FILTERS
#define FEAT 15
#define L_ENC 168
#define HID 128
#define R 16          // batch rows per block = MFMA M tile
#define BLK 256       // 4 waves
#define FP 72         // padded row stride (h16) for 16-row activation tiles

__device__ __forceinline__ floatx4 mfma16(half8 a, half8 b, floatx4 c) {
  return __builtin_amdgcn_mfma_f32_16x16x32_f16(a, b, c, 0, 0, 0);
}

// LDS-producer barrier. The time loop is 100% free of consumed global loads,
// so even a conservative vmcnt drain here would find the counter near 0.
#define BAR() asm volatile("s_waitcnt lgkmcnt(0)\n\ts_barrier" ::: "memory")

// tanh via hardware exp2 + rcp (~1 ulp each; error << f16 budget)
__device__ __forceinline__ float tanh_fast(float x) {
  float cx = fminf(fmaxf(x, -15.f), 15.f);
  float e  = __builtin_amdgcn_exp2f(-2.885390081777927f * cx);   // e^{-2x}
  return (1.f - e) * __builtin_amdgcn_rcpf(1.f + e);
}
// tanh(f) * sigmoid(g) with a single rcp
__device__ __forceinline__ float gate_fast(float f, float g) {
  float cf = fminf(fmaxf(f, -15.f), 15.f);
  float cg = fminf(fmaxf(g, -30.f), 30.f);
  float ef = __builtin_amdgcn_exp2f(-2.885390081777927f * cf);   // e^{-2f}
  float eg = __builtin_amdgcn_exp2f(-1.4426950408889634f * cg);  // e^{-g}
  return (1.f - ef) * __builtin_amdgcn_rcpf((1.f + ef) * (1.f + eg));
}

// prep: W5 (384x128 f32, row-major) -> f16 B-frag layout in ws:
// idx = ((ktg*8 + nt)*64 + lane)*8 + j ; value = W5[ktg*32 + (lane>>4)*8 + j][nt*16 + (lane&15)]
__global__ void prep_w5(const float* __restrict__ gW5, h16* __restrict__ wsW5) {
  int t = blockIdx.x * 256 + threadIdx.x;     // 0..6143
  if (t >= 12 * 8 * 64) return;
  int lane = t & 63, nt = (t >> 6) & 7, ktg = t >> 9;
  int n  = nt * 16 + (lane & 15);
  int kb = ktg * 32 + (lane >> 4) * 8;
  half8 v;
  #pragma unroll
  for (int j = 0; j < 8; ++j) v[j] = (h16)gW5[(size_t)(kb + j) * C2 + n];
  *(half8*)&wsW5[(size_t)t * 8] = v;
}

// v9: v8 design (global-free time loop) with LDS trimmed 160000 -> 146176 B.
//  - featH is [24][16][16]; k>=16 zero half of W1 A-frag comes from registers.
//  - y stored straight to global in-loop (fire-and-forget; BAR has no vmcnt).
// Everything else identical to v8: encoder tails pre-staged into ring/enc5 LDS,
// all weights+biases in registers, raw s_barrier, exp2-based activations,
// y recurrence re-derived per-lane from ypartS.
__global__ __launch_bounds__(BLK, 1) void decoder_v9(
    const float* __restrict__ dec_feat,   // (B,24,15)
    const float* __restrict__ dec_init,   // (B,1)
    const float* __restrict__ enc,        // (6,B,168,64)
    const float* __restrict__ gW1, const float* __restrict__ gb1,
    const float* __restrict__ gW2, const float* __restrict__ gb2,
    const float* __restrict__ gW3,
    const float* __restrict__ gW4, const float* __restrict__ gb4,
    const h16*  __restrict__ wsW5, const float* __restrict__ gb5,
    const float* __restrict__ gW6, const float* __restrict__ gb6,
    float* __restrict__ out)              // (B,24)
{
  __shared__ alignas(16) h16 ringL[31][R][FP];      // 71424B: layer i base = 2^i-1
  __shared__ alignas(16) h16 enc5L[T_STEPS][R][FP]; // 55296B: layer5 stat (always enc)
  __shared__ alignas(16) h16 xH[R][FP];             // 2304B
  __shared__ alignas(16) h16 gatedH[R][FP];         // 2304B
  __shared__ alignas(16) h16 skipH[R][FP];          // 2304B
  __shared__ alignas(16) h16 featH[T_STEPS][R][16]; // 12288B: [0]=y slot, 1..15 feats
  __shared__ alignas(16) float ypartS[R][4];        // 256B: per-wave partial y

  const int tid  = threadIdx.x;
  const int w    = tid >> 6;        // wave 0..3
  const int lane = tid & 63;
  const int m16  = lane & 15;
  const int q    = lane >> 4;
  const int q8   = q * 8;
  const int b0   = blockIdx.x * R;
  const int col  = w * 16 + m16;    // 0..63, fixed per thread

  // ---- loop-invariant weights -> registers ----
  half8 rW1;
  #pragma unroll
  for (int j = 0; j < 8; ++j) {
    int k = q8 + j;
    rW1[j] = (k < 16) ? (h16)gW1[k * F + col] : (h16)0.0f;
  }
  half8 rW2[2][2], rW3[2][2], rW4[2][2];
  #pragma unroll
  for (int h = 0; h < 2; ++h) {
    int n = (w + 4 * h) * 16 + m16;
    #pragma unroll
    for (int kt = 0; kt < 2; ++kt) {
      half8 v2, v3, v4;
      #pragma unroll
      for (int j = 0; j < 8; ++j) {
        int k = kt * 32 + q8 + j;
        v2[j] = (h16)gW2[k * C2 + n];
        v3[j] = (h16)gW3[k * C2 + n];
        v4[j] = (h16)gW4[k * C2 + n];
      }
      rW2[h][kt] = v2; rW3[h][kt] = v3; rW4[h][kt] = v4;
    }
  }
  half8 w5r[6][4];
  #pragma unroll
  for (int i = 0; i < 6; ++i)
    #pragma unroll
    for (int kt = 0; kt < 2; ++kt)
      #pragma unroll
      for (int nn = 0; nn < 2; ++nn)
        w5r[i][kt * 2 + nn] =
            *(const half8*)&wsW5[(size_t)((((2 * i + kt) * 8) + (w + 4 * nn)) * 64 + lane) * 8];

  const float rb1  = gb1[col];
  const float rb2f = gb2[col], rb2g = gb2[64 + col];
  const float rb4s = gb4[col], rb4r = gb4[64 + col];
  const float rb5a = gb5[col], rb5b = gb5[64 + col];
  const float rw6a = gW6[col], rw6b = gW6[64 + col];
  const float rb6  = gb6[0];
  const float rInit = dec_init[b0 + m16];          // y_{-1} for step 0

  // ---- pre-stage encoder tails: ring slots (layers 0..4) + enc5 (layer 5) ----
  // Ring slot (2^i-1)+s (s<d) is exactly what layer i reads at step t=s before
  // any ring write lands there (ring is read-before-write each step).
  {
    int mm = tid >> 4, kk = (tid & 15) * 4;        // (row, filter group)
    #pragma unroll 1
    for (int it = 0; it < 55; ++it) {
      int i, s; h16* dst;
      if (it < 31) {                               // it == (2^i - 1) + s
        i = (it >= 15) ? 4 : (it >= 7) ? 3 : (it >= 3) ? 2 : (it >= 1) ? 1 : 0;
        s = it - ((1 << i) - 1);
        dst = &ringL[it][mm][kk];
      } else { i = 5; s = it - 31; dst = &enc5L[s][mm][kk]; }
      int d = 1 << i;
      const float* sp = enc + (((size_t)i * B_TOT + b0 + mm) * L_ENC + (L_ENC + s - d)) * F + kk;
      float4 v = *(const float4*)sp;
      half4 hv; hv[0] = (h16)v.x; hv[1] = (h16)v.y; hv[2] = (h16)v.z; hv[3] = (h16)v.w;
      *(half4*)dst = hv;
    }
  }
  // ---- pre-stage decoder features (whole rows per task: no zero/fill race) ----
  for (int p = tid; p < T_STEPS * R; p += BLK) {
    int tt = p >> 4, row = p & 15;
    const float* sp = dec_feat + (size_t)(b0 + row) * (T_STEPS * FEAT) + tt * FEAT;
    half8 v0, v1;
    v0[0] = (h16)0.0f;                             // y splice slot
    #pragma unroll
    for (int j = 0; j < 7; ++j) v0[1 + j] = (h16)sp[j];
    #pragma unroll
    for (int j = 0; j < 8; ++j) v1[j] = (h16)sp[7 + j];
    *(half8*)&featH[tt][row][0] = v0;
    *(half8*)&featH[tt][row][8] = v1;
  }
  __syncthreads();

  // stat A-frag loader: pure LDS; i is always a compile-time constant.
  auto loadStat = [&](half8* dst, int i, int t) {
    const h16* p;
    if (i == 5) p = &enc5L[t][m16][0];
    else {
      const int d = 1 << i;
      p = &ringL[((1 << i) - 1) + (t & (d - 1))][m16][0];
    }
    dst[0] = *(const half8*)(p + q8);
    dst[1] = *(const half8*)(p + 32 + q8);
  };

  float xr[4];   // fp32 residual-stream master, (row=q*4+j, col) fixed per lane

  for (int t = 0; t < T_STEPS; ++t) {
    // ---- y recurrence: every lane re-derives y_{t-1} from ypartS ----
    float yv;
    if (t == 0) yv = rInit;
    else {
      float4 yp = *(const float4*)&ypartS[m16][0];
      yv = (yp.x + yp.y + yp.z + yp.w) + rb6;
    }
    if (t > 0 && w == 0 && q == 0)
      out[(size_t)(b0 + m16) * T_STEPS + (t - 1)] = yv;   // fire-and-forget

    // ---- W1: x = tanh(cur @ W1 + b1) ----
    half8 aCur;
    if (q < 2) {
      aCur = *(const half8*)&featH[t][m16][q8];           // k 0..15
    } else {
      #pragma unroll
      for (int j = 0; j < 8; ++j) aCur[j] = (h16)0.0f;    // k 16..31 pad
    }
    if (q == 0) aCur[0] = (h16)yv;                        // splice y into k=0
    floatx4 accX = {0.f, 0.f, 0.f, 0.f};
    accX = mfma16(aCur, rW1, accX);
    half8 stat[2];
    loadStat(stat, 0, t);                                 // stat for dilation 0
    #pragma unroll
    for (int j = 0; j < 4; ++j) {
      float v = tanh_fast(accX[j] + rb1);
      xr[j] = v;
      xH[q * 4 + j][col] = (h16)v;
    }
    BAR();                                                // B1: xH ready

    floatx4 hAccA = {0.f, 0.f, 0.f, 0.f};                 // W5 acc, nt=w
    floatx4 hAccB = {0.f, 0.f, 0.f, 0.f};                 // W5 acc, nt=w+4

    #pragma unroll
    for (int i = 0; i < 6; ++i) {
      const int d = 1 << i;
      half8 xA0 = *(const half8*)&xH[m16][q8];
      half8 xA1 = *(const half8*)&xH[m16][32 + q8];
      half8 stN[2];
      if (i < 5) loadStat(stN, i + 1, t);                 // prefetch next dilation (LDS)

      // phase A: dil = stat@W2 + x@W3 (+b2)
      floatx4 aF = {0.f, 0.f, 0.f, 0.f}, aG = {0.f, 0.f, 0.f, 0.f};
      aF = mfma16(stat[0], rW2[0][0], aF);
      aF = mfma16(stat[1], rW2[0][1], aF);
      aF = mfma16(xA0,     rW3[0][0], aF);
      aF = mfma16(xA1,     rW3[0][1], aF);
      aG = mfma16(stat[0], rW2[1][0], aG);
      aG = mfma16(stat[1], rW2[1][1], aG);
      aG = mfma16(xA0,     rW3[1][0], aG);
      aG = mfma16(xA1,     rW3[1][1], aG);
      #pragma unroll
      for (int j = 0; j < 4; ++j)
        gatedH[q * 4 + j][col] = (h16)gate_fast(aF[j] + rb2f, aG[j] + rb2g);
      BAR();                                              // B2a: gatedH ready

      // phase B: o = gated @ W4 + b4 ; skip cols 0..63, residual 64..127
      half8 gA0 = *(const half8*)&gatedH[m16][q8];
      half8 gA1 = *(const half8*)&gatedH[m16][32 + q8];
      floatx4 oS = {0.f, 0.f, 0.f, 0.f}, oR = {0.f, 0.f, 0.f, 0.f};
      oS = mfma16(gA0, rW4[0][0], oS);
      oS = mfma16(gA1, rW4[0][1], oS);
      oR = mfma16(gA0, rW4[1][0], oR);
      oR = mfma16(gA1, rW4[1][1], oR);
      #pragma unroll
      for (int j = 0; j < 4; ++j) {
        int row = q * 4 + j;
        float s = oS[j] + rb4s;
        skipH[row][col] = (h16)fmaxf(s, 0.0f);
        float xn = xr[j] + oR[j] + rb4r;                  // fp32 master update
        xr[j] = xn;
        h16 hx = (h16)xn;
        xH[row][col] = hx;
        if (i < 5) ringL[((1 << i) - 1) + (t & (d - 1))][row][col] = hx;
      }
      BAR();                                              // B2b: skipH/xH/ring ready

      // W5 skip-chunk i (register B-frags)
      half8 sk0 = *(const half8*)&skipH[m16][q8];
      half8 sk1 = *(const half8*)&skipH[m16][32 + q8];
      hAccA = mfma16(sk0, w5r[i][0], hAccA);
      hAccA = mfma16(sk1, w5r[i][2], hAccA);
      hAccB = mfma16(sk0, w5r[i][1], hAccB);
      hAccB = mfma16(sk1, w5r[i][3], hAccB);

      if (i < 5) { stat[0] = stN[0]; stat[1] = stN[1]; }
    }

    // ---- h = relu(hAcc + b5); y-partials = h @ W6 ----
    {
      floatx4 vv;
      #pragma unroll
      for (int j = 0; j < 4; ++j) {
        float ha = fmaxf(hAccA[j] + rb5a, 0.0f);
        float hb = fmaxf(hAccB[j] + rb5b, 0.0f);
        vv[j] = ha * rw6a + hb * rw6b;
      }
      #pragma unroll
      for (int off = 1; off < 16; off <<= 1) {
        #pragma unroll
        for (int j = 0; j < 4; ++j) vv[j] += __shfl_xor(vv[j], off, 16);
      }
      if (m16 == 0) {
        #pragma unroll
        for (int j = 0; j < 4; ++j) ypartS[q * 4 + j][w] = vv[j];
      }
    }
    BAR();                                                // B3: ypartS ready
  }

  // final y (t = 23)
  {
    float4 yp = *(const float4*)&ypartS[m16][0];
    float yv = (yp.x + yp.y + yp.z + yp.w) + rb6;
    if (w == 0 && q == 0)
      out[(size_t)(b0 + m16) * T_STEPS + (T_STEPS - 1)] = yv;
  }
}

extern "C" void kernel_launch(void* const* d_in, const int* in_sizes, int n_in,
                              void* d_out, int out_size, void* d_ws, size_t ws_size,
                              hipStream_t stream) {
  const float* dec_feat = (const float*)d_in[0];
  const float* dec_init = (const float*)d_in[1];
  const float* enc      = (const float*)d_in[2];
  const float* W1 = (const float*)d_in[3];
  const float* b1 = (const float*)d_in[4];
  const float* W2 = (const float*)d_in[5];
  const float* b2 = (const float*)d_in[6];
  const float* W3 = (const float*)d_in[7];
  const float* W4 = (const float*)d_in[8];
  const float* b4 = (const float*)d_in[9];
  const float* W5 = (const float*)d_in[10];
  const float* b5 = (const float*)d_in[11];
  const float* W6 = (const float*)d_in[12];
  const float* b6 = (const float*)d_in[13];
  float* out = (float*)d_out;
  h16* wsW5 = (h16*)d_ws;

  prep_w5<<<24, 256, 0, stream>>>(W5, wsW5);
  decoder_v9<<<dim3(B_TOT / R), dim3(BLK), 0, stream>>>(
      dec_feat, dec_init, enc, W1, b1, W2, b2, W3, W4, b4, wsW5, b5, W6, b6, out);
}

// Round 4
// 440.730 us; speedup vs baseline: 1.2214x; 1.0147x over previous
//
#include <hip/hip_runtime.h>

typedef _Float16 h16;
typedef _Float16 half4 __attribute__((ext_vector_type(4)));
typedef _Float16 half8 __attribute__((ext_vector_type(8)));
typedef float floatx4 __attribute__((ext_vector_type(4)));

#define B_TOT 1024
#define T_STEPS 24
#define F 64          // FILTERS
#define C2 128        // 2*FILTERS
#define FEAT 15
#define L_ENC 168
#define HID 128
#define R 16          // batch rows per block = MFMA M tile
#define BLK 256       // 4 waves
#define FP 72         // padded row stride (h16) for 16-row activation tiles

__device__ __forceinline__ floatx4 mfma16(half8 a, half8 b, floatx4 c) {
  return __builtin_amdgcn_mfma_f32_16x16x32_f16(a, b, c, 0, 0, 0);
}

// LDS-producer barrier (time loop has no consumed global loads in flight).
#define BAR() asm volatile("s_waitcnt lgkmcnt(0)\n\ts_barrier" ::: "memory")

// Keep-alive pin (rule 17): forces the value to stay materialized in VGPRs
// across the loop body instead of being rematerialized as a global load.
#define PIN(x) asm volatile("" : "+v"(x))

// tanh via hardware exp2 + rcp
__device__ __forceinline__ float tanh_fast(float x) {
  float cx = fminf(fmaxf(x, -15.f), 15.f);
  float e  = __builtin_amdgcn_exp2f(-2.885390081777927f * cx);   // e^{-2x}
  return (1.f - e) * __builtin_amdgcn_rcpf(1.f + e);
}
// tanh(f) * sigmoid(g) with a single rcp
__device__ __forceinline__ float gate_fast(float f, float g) {
  float cf = fminf(fmaxf(f, -15.f), 15.f);
  float cg = fminf(fmaxf(g, -30.f), 30.f);
  float ef = __builtin_amdgcn_exp2f(-2.885390081777927f * cf);   // e^{-2f}
  float eg = __builtin_amdgcn_exp2f(-1.4426950408889634f * cg);  // e^{-g}
  return (1.f - ef) * __builtin_amdgcn_rcpf((1.f + ef) * (1.f + eg));
}

// prep: W5 (384x128 f32, row-major) -> f16 frag layout in ws:
// idx = ((ktg*8 + nt)*64 + lane)*8 + j ; value = W5[ktg*32 + (lane>>4)*8 + j][nt*16 + (lane&15)]
__global__ void prep_w5(const float* __restrict__ gW5, h16* __restrict__ wsW5) {
  int t = blockIdx.x * 256 + threadIdx.x;     // 0..6143
  if (t >= 12 * 8 * 64) return;
  int lane = t & 63, nt = (t >> 6) & 7, ktg = t >> 9;
  int n  = nt * 16 + (lane & 15);
  int kb = ktg * 32 + (lane >> 4) * 8;
  half8 v;
  #pragma unroll
  for (int j = 0; j < 8; ++j) v[j] = (h16)gW5[(size_t)(kb + j) * C2 + n];
  *(half8*)&wsW5[(size_t)t * 8] = v;
}

// v10: operand-swapped MFMAs + register-pinned weights.
//  - All matmuls computed transposed (W^T @ X^T): the per-lane A-frag layout of
//    W^T equals the per-lane B-frag layout of W (m89-verified mappings), so
//    weight registers and activation reads are UNCHANGED; outputs land as
//    (batch=lane&15, filters w*16+q*4..+3) per lane -> every activation LDS
//    write is one aligned b64 store (was 4 strided b16), biases are per-lane
//    float4s, head reduction is 3 adds + 2 shuffles.
//  - PIN() keep-alives inside the t-loop force weight/bias residency in VGPRs
//    (R3 showed VGPR_Count=124 < 148 weight VGPRs -> compiler was re-loading
//    weights from global inside the loop).
//  - Split accumulators (depth-2 MFMA chains + VALU add) shorten dep chains.
__global__ __launch_bounds__(BLK, 1) void decoder_v10(
    const float* __restrict__ dec_feat,   // (B,24,15)
    const float* __restrict__ dec_init,   // (B,1)
    const float* __restrict__ enc,        // (6,B,168,64)
    const float* __restrict__ gW1, const float* __restrict__ gb1,
    const float* __restrict__ gW2, const float* __restrict__ gb2,
    const float* __restrict__ gW3,
    const float* __restrict__ gW4, const float* __restrict__ gb4,
    const h16*  __restrict__ wsW5, const float* __restrict__ gb5,
    const float* __restrict__ gW6, const float* __restrict__ gb6,
    float* __restrict__ out)              // (B,24)
{
  __shared__ alignas(16) h16 ringL[31][R][FP];      // 71424B: layer i base = 2^i-1
  __shared__ alignas(16) h16 enc5L[T_STEPS][R][FP]; // 55296B: layer5 stat (always enc)
  __shared__ alignas(16) h16 xH[R][FP];             // 2304B
  __shared__ alignas(16) h16 gatedH[R][FP];         // 2304B
  __shared__ alignas(16) h16 skipH[R][FP];          // 2304B
  __shared__ alignas(16) h16 featH[T_STEPS][R][16]; // 12288B: [0]=y slot, 1..15 feats
  __shared__ alignas(16) float ypartS[R][4];        // 256B

  const int tid  = threadIdx.x;
  const int w    = tid >> 6;        // wave 0..3
  const int lane = tid & 63;
  const int m16  = lane & 15;       // batch row owned by this lane (outputs)
  const int q    = lane >> 4;
  const int q8   = q * 8;
  const int b0   = blockIdx.x * R;
  const int col4 = w * 16 + q * 4;  // first of 4 filters owned by this lane

  // ---- loop-invariant weights -> registers (same contents as v9) ----
  half8 rW1;
  #pragma unroll
  for (int j = 0; j < 8; ++j) {
    int k = q8 + j;
    rW1[j] = (k < 16) ? (h16)gW1[k * F + (w * 16 + m16)] : (h16)0.0f;
  }
  half8 rW2[2][2], rW3[2][2], rW4[2][2];
  #pragma unroll
  for (int h = 0; h < 2; ++h) {
    int n = (w + 4 * h) * 16 + m16;
    #pragma unroll
    for (int kt = 0; kt < 2; ++kt) {
      half8 v2, v3, v4;
      #pragma unroll
      for (int j = 0; j < 8; ++j) {
        int k = kt * 32 + q8 + j;
        v2[j] = (h16)gW2[k * C2 + n];
        v3[j] = (h16)gW3[k * C2 + n];
        v4[j] = (h16)gW4[k * C2 + n];
      }
      rW2[h][kt] = v2; rW3[h][kt] = v3; rW4[h][kt] = v4;
    }
  }
  half8 w5r[6][4];
  #pragma unroll
  for (int i = 0; i < 6; ++i)
    #pragma unroll
    for (int kt = 0; kt < 2; ++kt)
      #pragma unroll
      for (int nn = 0; nn < 2; ++nn)
        w5r[i][kt * 2 + nn] =
            *(const half8*)&wsW5[(size_t)((((2 * i + kt) * 8) + (w + 4 * nn)) * 64 + lane) * 8];

  // per-lane bias / head quads (4 consecutive filters col4..col4+3)
  floatx4 rb1v  = *(const floatx4*)&gb1[col4];
  floatx4 rb2fv = *(const floatx4*)&gb2[col4];
  floatx4 rb2gv = *(const floatx4*)&gb2[64 + col4];
  floatx4 rb4sv = *(const floatx4*)&gb4[col4];
  floatx4 rb4rv = *(const floatx4*)&gb4[64 + col4];
  floatx4 rb5av = *(const floatx4*)&gb5[col4];
  floatx4 rb5bv = *(const floatx4*)&gb5[64 + col4];
  floatx4 rw6av = *(const floatx4*)&gW6[col4];
  floatx4 rw6bv = *(const floatx4*)&gW6[64 + col4];
  const float rb6   = gb6[0];
  const float rInit = dec_init[b0 + m16];          // y_{-1} for batch m16

  // ---- pre-stage encoder tails: ring slots (layers 0..4) + enc5 (layer 5) ----
  {
    int mm = tid >> 4, kk = (tid & 15) * 4;        // (row, filter group)
    #pragma unroll 1
    for (int it = 0; it < 55; ++it) {
      int i, s; h16* dst;
      if (it < 31) {                               // it == (2^i - 1) + s
        i = (it >= 15) ? 4 : (it >= 7) ? 3 : (it >= 3) ? 2 : (it >= 1) ? 1 : 0;
        s = it - ((1 << i) - 1);
        dst = &ringL[it][mm][kk];
      } else { i = 5; s = it - 31; dst = &enc5L[s][mm][kk]; }
      int d = 1 << i;
      const float* sp = enc + (((size_t)i * B_TOT + b0 + mm) * L_ENC + (L_ENC + s - d)) * F + kk;
      float4 v = *(const float4*)sp;
      half4 hv; hv[0] = (h16)v.x; hv[1] = (h16)v.y; hv[2] = (h16)v.z; hv[3] = (h16)v.w;
      *(half4*)dst = hv;
    }
  }
  // ---- pre-stage decoder features ----
  for (int p = tid; p < T_STEPS * R; p += BLK) {
    int tt = p >> 4, row = p & 15;
    const float* sp = dec_feat + (size_t)(b0 + row) * (T_STEPS * FEAT) + tt * FEAT;
    half8 v0, v1;
    v0[0] = (h16)0.0f;                             // y splice slot
    #pragma unroll
    for (int j = 0; j < 7; ++j) v0[1 + j] = (h16)sp[j];
    #pragma unroll
    for (int j = 0; j < 8; ++j) v1[j] = (h16)sp[7 + j];
    *(half8*)&featH[tt][row][0] = v0;
    *(half8*)&featH[tt][row][8] = v1;
  }
  __syncthreads();

  // stat B-frag loader: lane reads [m16][q8] / [m16][32+q8] (same data as the
  // old A-frag -- layouts coincide; see header comment).
  auto loadStat = [&](half8* dst, int i, int t) {
    const h16* p;
    if (i == 5) p = &enc5L[t][m16][0];
    else {
      const int d = 1 << i;
      p = &ringL[((1 << i) - 1) + (t & (d - 1))][m16][0];
    }
    dst[0] = *(const half8*)(p + q8);
    dst[1] = *(const half8*)(p + 32 + q8);
  };

  float xr[4];   // fp32 residual master: batch m16, filters col4+j

  for (int t = 0; t < T_STEPS; ++t) {
    // ---- pin weights/biases: forbid rematerialization as in-loop loads ----
    PIN(rW1);
    #pragma unroll
    for (int h = 0; h < 2; ++h)
      #pragma unroll
      for (int kt = 0; kt < 2; ++kt) { PIN(rW2[h][kt]); PIN(rW3[h][kt]); PIN(rW4[h][kt]); }
    #pragma unroll
    for (int i = 0; i < 6; ++i)
      #pragma unroll
      for (int k = 0; k < 4; ++k) PIN(w5r[i][k]);
    PIN(rb1v); PIN(rb2fv); PIN(rb2gv); PIN(rb4sv); PIN(rb4rv);
    PIN(rb5av); PIN(rb5bv); PIN(rw6av); PIN(rw6bv);

    // ---- y recurrence: every lane re-derives y_{t-1} ----
    float yv;
    if (t == 0) yv = rInit;
    else {
      float4 yp = *(const float4*)&ypartS[m16][0];
      yv = (yp.x + yp.y + yp.z + yp.w) + rb6;
    }
    if (t > 0 && w == 0 && q == 0)
      out[(size_t)(b0 + m16) * T_STEPS + (t - 1)] = yv;   // fire-and-forget

    // ---- W1 (swapped): x^T = W1^T @ cur^T ----
    half8 bCur;
    if (q < 2) {
      bCur = *(const half8*)&featH[t][m16][q8];           // k 0..15
    } else {
      #pragma unroll
      for (int j = 0; j < 8; ++j) bCur[j] = (h16)0.0f;    // k 16..31 pad
    }
    if (q == 0) bCur[0] = (h16)yv;                        // splice y at k=0
    floatx4 accX = {0.f, 0.f, 0.f, 0.f};
    accX = mfma16(rW1, bCur, accX);
    half8 stat[2];
    loadStat(stat, 0, t);
    half4 xv;
    #pragma unroll
    for (int j = 0; j < 4; ++j) {
      float v = tanh_fast(accX[j] + rb1v[j]);
      xr[j] = v;
      xv[j] = (h16)v;
    }
    *(half4*)&xH[m16][col4] = xv;                         // one b64 store
    BAR();                                                // B1: xH ready

    floatx4 hAccA = {0.f, 0.f, 0.f, 0.f};                 // hid rows w*16+q*4+j
    floatx4 hAccB = {0.f, 0.f, 0.f, 0.f};                 // hid rows 64+w*16+q*4+j

    #pragma unroll
    for (int i = 0; i < 6; ++i) {
      const int d = 1 << i;
      half8 xB0 = *(const half8*)&xH[m16][q8];
      half8 xB1 = *(const half8*)&xH[m16][32 + q8];
      half8 stN[2];
      if (i < 5) loadStat(stN, i + 1, t);                 // prefetch next dilation

      // phase A (swapped): dil^T = W2^T@stat^T + W3^T@x^T, split accumulators
      floatx4 aF0 = {0.f,0.f,0.f,0.f}, aF1 = {0.f,0.f,0.f,0.f};
      floatx4 aG0 = {0.f,0.f,0.f,0.f}, aG1 = {0.f,0.f,0.f,0.f};
      aF0 = mfma16(rW2[0][0], stat[0], aF0);
      aF1 = mfma16(rW2[0][1], stat[1], aF1);
      aG0 = mfma16(rW2[1][0], stat[0], aG0);
      aG1 = mfma16(rW2[1][1], stat[1], aG1);
      aF0 = mfma16(rW3[0][0], xB0, aF0);
      aF1 = mfma16(rW3[0][1], xB1, aF1);
      aG0 = mfma16(rW3[1][0], xB0, aG0);
      aG1 = mfma16(rW3[1][1], xB1, aG1);
      half4 gv;
      #pragma unroll
      for (int j = 0; j < 4; ++j) {
        float f = aF0[j] + aF1[j] + rb2fv[j];
        float g = aG0[j] + aG1[j] + rb2gv[j];
        gv[j] = (h16)gate_fast(f, g);
      }
      *(half4*)&gatedH[m16][col4] = gv;                   // one b64 store
      BAR();                                              // B2a: gatedH ready

      // phase B (swapped): o^T = W4^T @ gated^T
      half8 gB0 = *(const half8*)&gatedH[m16][q8];
      half8 gB1 = *(const half8*)&gatedH[m16][32 + q8];
      floatx4 oS0 = {0.f,0.f,0.f,0.f}, oS1 = {0.f,0.f,0.f,0.f};
      floatx4 oR0 = {0.f,0.f,0.f,0.f}, oR1 = {0.f,0.f,0.f,0.f};
      oS0 = mfma16(rW4[0][0], gB0, oS0);
      oS1 = mfma16(rW4[0][1], gB1, oS1);
      oR0 = mfma16(rW4[1][0], gB0, oR0);
      oR1 = mfma16(rW4[1][1], gB1, oR1);
      half4 sv, xv2;
      #pragma unroll
      for (int j = 0; j < 4; ++j) {
        float s = oS0[j] + oS1[j] + rb4sv[j];
        sv[j] = (h16)fmaxf(s, 0.0f);
        float xn = xr[j] + (oR0[j] + oR1[j] + rb4rv[j]);  // fp32 master update
        xr[j] = xn;
        xv2[j] = (h16)xn;
      }
      *(half4*)&skipH[m16][col4] = sv;
      *(half4*)&xH[m16][col4]   = xv2;
      if (i < 5) *(half4*)&ringL[((1 << i) - 1) + (t & (d - 1))][m16][col4] = xv2;
      BAR();                                              // B2b: skipH/xH/ring ready

      // W5 skip-chunk i (swapped; register A-frags)
      half8 sB0 = *(const half8*)&skipH[m16][q8];
      half8 sB1 = *(const half8*)&skipH[m16][32 + q8];
      hAccA = mfma16(w5r[i][0], sB0, hAccA);
      hAccA = mfma16(w5r[i][2], sB1, hAccA);
      hAccB = mfma16(w5r[i][1], sB0, hAccB);
      hAccB = mfma16(w5r[i][3], sB1, hAccB);

      if (i < 5) { stat[0] = stN[0]; stat[1] = stN[1]; }
    }

    // ---- head: y-partial = sum_j relu(h+b5)*W6 over this lane's 8 hid rows ----
    {
      float vv = 0.f;
      #pragma unroll
      for (int j = 0; j < 4; ++j) {
        vv += fmaxf(hAccA[j] + rb5av[j], 0.0f) * rw6av[j];
        vv += fmaxf(hAccB[j] + rb5bv[j], 0.0f) * rw6bv[j];
      }
      vv += __shfl_xor(vv, 16);
      vv += __shfl_xor(vv, 32);                           // all lanes: wave-sum for batch m16
      if (q == 0) ypartS[m16][w] = vv;
    }
    BAR();                                                // B3: ypartS ready
  }

  // final y (t = 23)
  {
    float4 yp = *(const float4*)&ypartS[m16][0];
    float yv = (yp.x + yp.y + yp.z + yp.w) + rb6;
    if (w == 0 && q == 0)
      out[(size_t)(b0 + m16) * T_STEPS + (T_STEPS - 1)] = yv;
  }
}

extern "C" void kernel_launch(void* const* d_in, const int* in_sizes, int n_in,
                              void* d_out, int out_size, void* d_ws, size_t ws_size,
                              hipStream_t stream) {
  const float* dec_feat = (const float*)d_in[0];
  const float* dec_init = (const float*)d_in[1];
  const float* enc      = (const float*)d_in[2];
  const float* W1 = (const float*)d_in[3];
  const float* b1 = (const float*)d_in[4];
  const float* W2 = (const float*)d_in[5];
  const float* b2 = (const float*)d_in[6];
  const float* W3 = (const float*)d_in[7];
  const float* W4 = (const float*)d_in[8];
  const float* b4 = (const float*)d_in[9];
  const float* W5 = (const float*)d_in[10];
  const float* b5 = (const float*)d_in[11];
  const float* W6 = (const float*)d_in[12];
  const float* b6 = (const float*)d_in[13];
  float* out = (float*)d_out;
  h16* wsW5 = (h16*)d_ws;

  prep_w5<<<24, 256, 0, stream>>>(W5, wsW5);
  decoder_v10<<<dim3(B_TOT / R), dim3(BLK), 0, stream>>>(
      dec_feat, dec_init, enc, W1, b1, W2, b2, W3, W4, b4, wsW5, b5, W6, b6, out);
}